// Round 10
// baseline (2797.199 us; speedup 1.0000x reference)
//
#include <hip/hip_runtime.h>
#include <cstdint>
#include <cstddef>

#define EMBED  256
#define HIDDEN 512
#define VOCAB  32000
#define BATCH  16
#define TCAP   63
#define STEPS  1024   // BATCH * (T+1)
#define GROWS  2048   // 4 * HIDDEN gate rows
#define NTILE_M 8     // 1024/128
#define NTILE_N 250   // 32000/128
#define NTILES  (NTILE_M * NTILE_N)
#define DYN_LDS 86016 // 84 KB -> 1 WG/CU (160 KB LDS/CU)

// ws layout (bytes)
#define WS_HBUF 0                      // u64[2][512] tagged h exchange (8 KB)
#define WS_CTRL 8192                   // u32: [0..31] progress, [32] ticket, [48] bcast
#define WS_HSU  16384                  // u32[1024][256] packed-bf16 hs trace (1 MB)
#define WS_XP   (16384 + 1048576)      // fp32[1024][2048] xp (8 MB)
#define WS_NEED (16384 + 1048576 + 8388608ull)

typedef __bf16 bf16x8 __attribute__((ext_vector_type(8)));
typedef float  f32x4  __attribute__((ext_vector_type(4)));
typedef unsigned int u32x4v __attribute__((ext_vector_type(4)));

// ---------------------------------------------------------------------------
// helpers
// ---------------------------------------------------------------------------
__device__ __forceinline__ float sigmoid_f(float x) {
    return 1.0f / (1.0f + __expf(-x));
}
__device__ __forceinline__ float tanh_f(float x) {
    float a = fabsf(x);
    float e = __expf(-2.0f * a);
    float r = (1.0f - e) / (1.0f + e);
    return copysignf(r, x);
}
__device__ __forceinline__ float sel4(float a0, float a1, float a2, float a3, int j) {
    float lo = (j & 1) ? a1 : a0;
    float hi = (j & 1) ? a3 : a2;
    return (j & 2) ? hi : lo;
}
__device__ __forceinline__ unsigned short f2bf_u16(float f) {
    union { float f; unsigned u; } v; v.f = f;
    unsigned r = v.u + 0x7fffu + ((v.u >> 16) & 1u);
    return (unsigned short)(r >> 16);
}

// ---------------------------------------------------------------------------
// Kernel 0: xp[s][r] = xs[s].W_ih[r] + b_ih[r] + b_hh[r]   (fp32 GEMM)
// ---------------------------------------------------------------------------
__global__ __launch_bounds__(256) void xproj_kernel(
    const float* __restrict__ features,
    const int*   __restrict__ captions,
    const float* __restrict__ emb,
    const float* __restrict__ W_ih,
    const float* __restrict__ b_ih,
    const float* __restrict__ b_hh,
    float* __restrict__ xp)            // [STEPS][GROWS]
{
    __shared__ float As[64][65];
    __shared__ float Bs[64][65];
    const int tid = threadIdx.x;
    const int tx = tid & 15, ty = tid >> 4;
    const int r0 = blockIdx.x * 64;
    const int s0 = blockIdx.y * 64;
    float accv[4][4] = {};

    for (int k0 = 0; k0 < EMBED; k0 += 64) {
#pragma unroll
        for (int i = 0; i < 4; ++i) {
            const int idx = tid + i * 256;
            const int row = idx >> 4, q = idx & 15;
            const int s = s0 + row, sb = s >> 6, st = s & 63;
            const float* xr = (st == 0)
                ? (features + (size_t)sb * EMBED)
                : (emb + (size_t)captions[sb * TCAP + st - 1] * EMBED);
            const float4 a = *(const float4*)(xr + k0 + q * 4);
            As[row][q * 4 + 0] = a.x; As[row][q * 4 + 1] = a.y;
            As[row][q * 4 + 2] = a.z; As[row][q * 4 + 3] = a.w;
            const float4 b = *(const float4*)(W_ih + (size_t)(r0 + row) * EMBED + k0 + q * 4);
            Bs[row][q * 4 + 0] = b.x; Bs[row][q * 4 + 1] = b.y;
            Bs[row][q * 4 + 2] = b.z; Bs[row][q * 4 + 3] = b.w;
        }
        __syncthreads();
#pragma unroll 16
        for (int kk = 0; kk < 64; ++kk) {
            float av[4], bv[4];
#pragma unroll
            for (int i = 0; i < 4; ++i) av[i] = As[ty * 4 + i][kk];
#pragma unroll
            for (int j = 0; j < 4; ++j) bv[j] = Bs[tx * 4 + j][kk];
#pragma unroll
            for (int i = 0; i < 4; ++i)
#pragma unroll
                for (int j = 0; j < 4; ++j)
                    accv[i][j] = fmaf(av[i], bv[j], accv[i][j]);
        }
        __syncthreads();
    }
#pragma unroll
    for (int j = 0; j < 4; ++j) {
        const int r = r0 + tx * 4 + j;
        const float bb = b_ih[r] + b_hh[r];
#pragma unroll
        for (int i = 0; i < 4; ++i)
            xp[(size_t)(s0 + ty * 4 + i) * GROWS + r] = accv[i][j] + bb;
    }
}

// ---------------------------------------------------------------------------
// Kernel 1 (fused): 32 scan WGs + 1 scout WG + 223 GEMM worker WGs.
// 84 KB dynamic LDS forces 1 WG/CU: every scan WG owns its CU exclusively.
//
// SCAN (blockIdx < 32): round-4 transport (proven): shared tagged
//   hbuf[2][512] (s+1)<<32|h_bits, relaxed agent stores; poll = ONE
//   fused-asm dwordx4 sc0 sc1 + vmcnt(0) (split issue/wait = round-6/7
//   regalloc hazard); hlds exchange via __syncthreads (raw s_barrier is
//   IntrNoMem — round-6 lesson). Progress ctrl[g]=s after the barrier
//   (barrier's vmcnt(0) drain makes rows < s globally visible). Trace:
//   packed bf16-pair u32 agent stores to hsu. Scan WGs join workers after.
//
// SCOUT (blockIdx == 32): ONLY reader of ctrl[0..31] (every ~512 cy);
//   publishes min to bcast word ctrl[48]. Removes the round-9 poll storm
//   from the scan's ctrl stores (which each step's __syncthreads drains —
//   that queueing was the +460us interference).
//
// WORKERS: persistent; ticket = atomicAdd(ctrl[32]) -> tile t (m-major).
//   Gate: bcast >= (mb+1)*128+16 (single word, single writer, s_sleep).
//   Tile: 128x128, BK=64, 16x16x32 bf16 MFMA, XOR-swizzled LDS; A from hsu
//   (bf16 pairs), B converts W_out fp32->bf16 during staging.
//   Deadlock-free: scan+scout dispatched first; workers exit when no tiles.
// ---------------------------------------------------------------------------
__global__ __launch_bounds__(256, 1) void fused_kernel(
    const float* __restrict__ W_hh,
    const float* __restrict__ xp,              // [STEPS][GROWS]
    unsigned long long* __restrict__ hbuf,     // [2][HIDDEN]
    unsigned* __restrict__ ctrl,               // [0..31] prog, [32] ticket, [48] bcast
    unsigned* __restrict__ hsu,                // [STEPS][256] packed bf16 pairs
    const float* __restrict__ W_out,
    const float* __restrict__ b_out,
    float* __restrict__ out)
{
    extern __shared__ char smem[];
    __shared__ int sh_t;
    __shared__ unsigned sh_mn;
    const int tid = threadIdx.x;
    const int rg  = tid >> 6;
    const int kc  = tid & 63;
    const int g   = blockIdx.x;

    if (g < 32) {
        // =================== SCAN ===================
        float (*hlds)[HIDDEN] = (float (*)[HIDDEN])smem;
        const int w  = g * 4 + rg;
        const int j0 = w * 4;

        const int t_own  = ((kc & 1) << 1) | ((kc >> 1) & 1);
        const int jj_own = (((kc >> 2) & 1) << 1) | ((kc >> 3) & 1);
        const int row_own = t_own * HIDDEN + j0 + jj_own;

        float Whh[4][4][8];
#pragma unroll
        for (int t = 0; t < 4; ++t) {
#pragma unroll
            for (int jj = 0; jj < 4; ++jj) {
                const int row = t * HIDDEN + j0 + jj;
                const float4* ph = (const float4*)(W_hh + (size_t)row * HIDDEN + kc * 8);
                const float4 h0 = ph[0], h1 = ph[1];
                Whh[t][jj][0] = h0.x; Whh[t][jj][1] = h0.y; Whh[t][jj][2] = h0.z; Whh[t][jj][3] = h0.w;
                Whh[t][jj][4] = h1.x; Whh[t][jj][5] = h1.y; Whh[t][jj][6] = h1.z; Whh[t][jj][7] = h1.w;
            }
        }

        float c_state = 0.0f;
        float xpv = xp[row_own];
        float xpv_next;
        const int qi = rg * 128 + kc * 2;

        for (int s = 0; s < STEPS; ++s) {
            const int p = s & 1;
            const unsigned expect = (unsigned)s;

            // ---- poll my quarter: load+wait fused in ONE asm ----
            const unsigned long long fa =
                (unsigned long long)(hbuf + (size_t)p * HIDDEN + qi);
            unsigned d0, d1;
            for (;;) {
                u32x4v v;
                asm volatile("global_load_dwordx4 %0, %1, off sc0 sc1\n\t"
                             "s_waitcnt vmcnt(0)"
                             : "=&v"(v) : "v"(fa) : "memory");
                if (__all((int)((v.y == expect) & (v.w == expect)))) {
                    d0 = v.x; d1 = v.z; break;
                }
            }

            hlds[p][qi]     = __uint_as_float(d0);
            hlds[p][qi + 1] = __uint_as_float(d1);
            __syncthreads();   // drains prior-step trace/ctrl stores too
            if (tid == 0)
                __hip_atomic_store(ctrl + g, (unsigned)s,
                                   __ATOMIC_RELAXED, __HIP_MEMORY_SCOPE_AGENT);

            float hreg[8];
            {
                const float4 a = *(const float4*)&hlds[p][kc * 8];
                const float4 b = *(const float4*)&hlds[p][kc * 8 + 4];
                hreg[0] = a.x; hreg[1] = a.y; hreg[2] = a.z; hreg[3] = a.w;
                hreg[4] = b.x; hreg[5] = b.y; hreg[6] = b.z; hreg[7] = b.w;
            }

            const int sn = (s + 1 < STEPS) ? (s + 1) : (STEPS - 1);
            xpv_next = xp[(size_t)sn * GROWS + row_own];

            float acc[16];
#pragma unroll
            for (int t = 0; t < 4; ++t) {
#pragma unroll
                for (int jj = 0; jj < 4; ++jj) {
                    float a = Whh[t][jj][0] * hreg[0];
#pragma unroll
                    for (int kk = 1; kk < 8; ++kk)
                        a = fmaf(Whh[t][jj][kk], hreg[kk], a);
                    acc[t * 4 + jj] = a;
                }
            }

#pragma unroll
            for (int i = 0; i < 8; ++i) {
                const float send = (kc & 1) ? acc[i] : acc[i + 8];
                const float keep = (kc & 1) ? acc[i + 8] : acc[i];
                acc[i] = keep + __shfl_xor(send, 1, 64);
            }
#pragma unroll
            for (int i = 0; i < 4; ++i) {
                const float send = (kc & 2) ? acc[i] : acc[i + 4];
                const float keep = (kc & 2) ? acc[i + 4] : acc[i];
                acc[i] = keep + __shfl_xor(send, 2, 64);
            }
#pragma unroll
            for (int i = 0; i < 2; ++i) {
                const float send = (kc & 4) ? acc[i] : acc[i + 2];
                const float keep = (kc & 4) ? acc[i + 2] : acc[i];
                acc[i] = keep + __shfl_xor(send, 4, 64);
            }
            {
                const float send = (kc & 8) ? acc[0] : acc[1];
                const float keep = (kc & 8) ? acc[1] : acc[0];
                acc[0] = keep + __shfl_xor(send, 8, 64);
            }
            float a = acc[0];
            a += __shfl_xor(a, 16, 64);
            a += __shfl_xor(a, 32, 64);
            a += xpv;

            const float g00 = a;
            const float g01 = __shfl_xor(a, 1, 64);
            const float g10 = __shfl_xor(a, 2, 64);
            const float g11 = __shfl_xor(g01, 2, 64);
            float gi = sel4(g00, g10, g01, g11, t_own);
            float gf = sel4(g00, g10, g01, g11, t_own ^ 1);
            float gg = sel4(g00, g10, g01, g11, t_own ^ 2);
            float go = sel4(g00, g10, g01, g11, t_own ^ 3);

            gi = sigmoid_f(gi);
            gf = sigmoid_f(gf);
            gg = tanh_f(gg);
            go = sigmoid_f(go);
            c_state = gf * c_state + gi * gg;
            const float hnew = go * tanh_f(c_state);

            // ---- publish version s+1 (critical path) ----
            const int q = (s + 1) & 1;
            if ((kc & 0x33) == 0) {
                const int j = j0 + jj_own;
                const unsigned long long pack =
                    ((unsigned long long)(unsigned)(s + 1) << 32) |
                    (unsigned long long)__float_as_uint(hnew);
                __hip_atomic_store(hbuf + (size_t)q * HIDDEN + j, pack,
                                   __ATOMIC_RELAXED, __HIP_MEMORY_SCOPE_AGENT);
            }
            // ---- trace: packed bf16 pair, agent-visible for workers ----
            const float part = __shfl(hnew, (kc + 8) & 63, 64);
            if (kc == 0 || kc == 4) {
                const unsigned pk = (unsigned)f2bf_u16(hnew) |
                                    ((unsigned)f2bf_u16(part) << 16);
                __hip_atomic_store(hsu + (size_t)s * 256 + (j0 >> 1) + (kc >> 2), pk,
                                   __ATOMIC_RELAXED, __HIP_MEMORY_SCOPE_AGENT);
            }

            xpv = xpv_next;
        }
        __syncthreads();   // drain final trace stores
        if (tid == 0)
            __hip_atomic_store(ctrl + g, (unsigned)STEPS,
                               __ATOMIC_RELAXED, __HIP_MEMORY_SCOPE_AGENT);
        __syncthreads();
        // fall through: join the worker pool
    } else if (g == 32) {
        // =================== SCOUT ===================
        for (;;) {
            if (tid < 64) {
                unsigned v = (kc < 32)
                    ? __hip_atomic_load(ctrl + kc, __ATOMIC_RELAXED,
                                        __HIP_MEMORY_SCOPE_AGENT)
                    : 0xffffffffu;
#pragma unroll
                for (int d = 1; d < 64; d <<= 1) {
                    const unsigned o = (unsigned)__shfl_xor((int)v, d, 64);
                    v = (o < v) ? o : v;
                }
                if (kc == 0) {
                    __hip_atomic_store(ctrl + 48, v, __ATOMIC_RELAXED,
                                       __HIP_MEMORY_SCOPE_AGENT);
                    sh_mn = v;
                }
            }
            __syncthreads();
            if (sh_mn >= (unsigned)STEPS) break;
            __builtin_amdgcn_s_sleep(8);
            __syncthreads();
        }
        // fall through: join the worker pool
    }

    // =================== GEMM WORKERS ===================
    char* AsR = smem;
    char* BsR = smem + 16384;
    const int lane = kc;
    const int wave = rg;
    const int wm = (wave >> 1) * 64;
    const int wn = (wave & 1) * 64;

    for (;;) {
        if (tid == 0)
            sh_t = (int)__hip_atomic_fetch_add(ctrl + 32, 1u,
                       __ATOMIC_RELAXED, __HIP_MEMORY_SCOPE_AGENT);
        __syncthreads();
        const int t = sh_t;
        if (t >= NTILES) break;
        const int mb = t / NTILE_N, nb = t % NTILE_N;
        const int m0 = mb * 128, n0 = nb * 128;

        // ---- gate on bcast word (single writer: scout) ----
        {
            const unsigned tgt = (mb < NTILE_M - 1)
                ? (unsigned)((mb + 1) * 128 + 16) : (unsigned)STEPS;
            for (;;) {
                const unsigned v = __hip_atomic_load(ctrl + 48,
                    __ATOMIC_RELAXED, __HIP_MEMORY_SCOPE_AGENT);
                if (v >= tgt) break;
                __builtin_amdgcn_s_sleep(16);
            }
        }

        f32x4 acc[4][4] = {};
        for (int k0 = 0; k0 < HIDDEN; k0 += 64) {
            if (k0) __syncthreads();
#pragma unroll
            for (int i = 0; i < 4; ++i) {
                const int o   = (tid + i * 256) << 4;
                const int row = o >> 7;
                const int cb  = o & 127;
                const int sc  = cb ^ ((row & 7) << 4);
                const u32x4v av = *(const u32x4v*)(hsu + (size_t)(m0 + row) * 256
                                                   + (k0 >> 1) + (cb >> 2));
                *(u32x4v*)(AsR + row * 128 + sc) = av;
                const float4 b0 = *(const float4*)(W_out + (size_t)(n0 + row) * HIDDEN
                                                   + k0 + (cb >> 1));
                const float4 b1 = *(const float4*)(W_out + (size_t)(n0 + row) * HIDDEN
                                                   + k0 + (cb >> 1) + 4);
                u32x4v bw;
                bw.x = (unsigned)f2bf_u16(b0.x) | ((unsigned)f2bf_u16(b0.y) << 16);
                bw.y = (unsigned)f2bf_u16(b0.z) | ((unsigned)f2bf_u16(b0.w) << 16);
                bw.z = (unsigned)f2bf_u16(b1.x) | ((unsigned)f2bf_u16(b1.y) << 16);
                bw.w = (unsigned)f2bf_u16(b1.z) | ((unsigned)f2bf_u16(b1.w) << 16);
                *(u32x4v*)(BsR + row * 128 + sc) = bw;
            }
            __syncthreads();
#pragma unroll
            for (int ks = 0; ks < 2; ++ks) {
                const int kb = ks * 64 + ((lane >> 4) << 4);
                bf16x8 af[4], bfr[4];
#pragma unroll
                for (int mi = 0; mi < 4; ++mi) {
                    const int r = wm + mi * 16 + (lane & 15);
                    af[mi] = *(const bf16x8*)(AsR + r * 128 + (kb ^ ((r & 7) << 4)));
                }
#pragma unroll
                for (int ni = 0; ni < 4; ++ni) {
                    const int r = wn + ni * 16 + (lane & 15);
                    bfr[ni] = *(const bf16x8*)(BsR + r * 128 + (kb ^ ((r & 7) << 4)));
                }
#pragma unroll
                for (int mi = 0; mi < 4; ++mi)
#pragma unroll
                    for (int ni = 0; ni < 4; ++ni)
                        acc[mi][ni] = __builtin_amdgcn_mfma_f32_16x16x32_bf16(
                            af[mi], bfr[ni], acc[mi][ni], 0, 0, 0);
            }
        }

#pragma unroll
        for (int ni = 0; ni < 4; ++ni) {
            const int col = n0 + wn + ni * 16 + (lane & 15);
            const float bo = b_out[col];
#pragma unroll
            for (int mi = 0; mi < 4; ++mi) {
                const int r0 = m0 + wm + mi * 16 + ((lane >> 4) << 2);
#pragma unroll
                for (int qq = 0; qq < 4; ++qq)
                    out[(size_t)(r0 + qq) * VOCAB + col] = acc[mi][ni][qq] + bo;
            }
        }
        __syncthreads();   // protect sh_t / LDS reuse across iterations
    }
}

// ---------------------------------------------------------------------------
// Kernel 2: in-place row softmax, one WG per row of 32000.
// ---------------------------------------------------------------------------
__global__ __launch_bounds__(256) void softmax_kernel(float* __restrict__ out)
{
    const int row = blockIdx.x;
    float* p = out + (size_t)row * VOCAB;
    const int tid = threadIdx.x;
    __shared__ float redm[4];
    __shared__ float reds[4];

    float m = -3.402823466e38f;
    for (int idx = tid * 4; idx < VOCAB; idx += 1024) {
        const float4 v = *(const float4*)(p + idx);
        m = fmaxf(m, fmaxf(fmaxf(v.x, v.y), fmaxf(v.z, v.w)));
    }
#pragma unroll
    for (int d = 1; d < 64; d <<= 1) m = fmaxf(m, __shfl_xor(m, d, 64));
    if ((tid & 63) == 0) redm[tid >> 6] = m;
    __syncthreads();
    m = fmaxf(fmaxf(redm[0], redm[1]), fmaxf(redm[2], redm[3]));

    float sum = 0.f;
    for (int idx = tid * 4; idx < VOCAB; idx += 1024) {
        const float4 v = *(const float4*)(p + idx);
        sum += __expf(v.x - m) + __expf(v.y - m) + __expf(v.z - m) + __expf(v.w - m);
    }
#pragma unroll
    for (int d = 1; d < 64; d <<= 1) sum += __shfl_xor(sum, d, 64);
    if ((tid & 63) == 0) reds[tid >> 6] = sum;
    __syncthreads();
    sum = reds[0] + reds[1] + reds[2] + reds[3];
    const float inv = 1.0f / sum;

    for (int idx = tid * 4; idx < VOCAB; idx += 1024) {
        const float4 v = *(const float4*)(p + idx);
        float4 o;
        o.x = __expf(v.x - m) * inv;
        o.y = __expf(v.y - m) * inv;
        o.z = __expf(v.z - m) * inv;
        o.w = __expf(v.w - m) * inv;
        *(float4*)(p + idx) = o;
    }
}

// ---------------------------------------------------------------------------
// launch: memset(ctrl+hbuf) -> xproj -> fused(scan+scout+GEMM) -> softmax
// ---------------------------------------------------------------------------
extern "C" void kernel_launch(void* const* d_in, const int* in_sizes, int n_in,
                              void* d_out, int out_size, void* d_ws, size_t ws_size,
                              hipStream_t stream)
{
    const float* features = (const float*)d_in[0];
    const int*   captions = (const int*)d_in[1];
    const float* emb      = (const float*)d_in[2];
    const float* W_ih     = (const float*)d_in[3];
    const float* W_hh     = (const float*)d_in[4];
    const float* b_ih     = (const float*)d_in[5];
    const float* b_hh     = (const float*)d_in[6];
    const float* W_out    = (const float*)d_in[7];
    const float* b_out    = (const float*)d_in[8];
    float* out = (float*)d_out;

    char* ws = (char*)d_ws;
    unsigned long long* hbuf = (unsigned long long*)(ws + WS_HBUF);
    unsigned*           ctrl = (unsigned*)(ws + WS_CTRL);
    unsigned*           hsu  = (unsigned*)(ws + WS_HSU);
    float*              xpb  = (float*)(ws + WS_XP);

    // reset exchange buffer + progress flags + ticket + bcast
    hipMemsetAsync(d_ws, 0, 16384, stream);

    xproj_kernel<<<dim3(GROWS / 64, STEPS / 64), 256, 0, stream>>>(
        features, captions, emb, W_ih, b_ih, b_hh, xpb);

    fused_kernel<<<256, 256, DYN_LDS, stream>>>(
        W_hh, xpb, hbuf, ctrl, hsu, W_out, b_out, out);

    softmax_kernel<<<STEPS, 256, 0, stream>>>(out);
}

// Round 11
// 1997.532 us; speedup vs baseline: 1.4003x; 1.4003x over previous
//
#include <hip/hip_runtime.h>
#include <cstdint>
#include <cstddef>

#define EMBED  256
#define HIDDEN 512
#define VOCAB  32000
#define BATCH  16
#define TCAP   63
#define STEPS  1024   // BATCH * (TCAP + 1)
#define GROWS  2048   // 4 * HIDDEN gate rows

// ws layout (bytes)  — round-4 proven layout
#define WS_HBUF  0          // u64 [2][512] tagged h words  (8 KB)
#define WS_HS32  8192       // float[1024][512]             (2 MB)
#define WS_HSBF  2105344    // bf16 [1024][512]             (1 MB)
#define WS_WB    3153920    // bf16 [32000][512]            (32 MB)
#define WS_XPOFF (24u * 1024u * 1024u)     // xp lives in Wb's tail 8 MB
#define WS_NEED  36708352ull
// Wb elements protected by xp overlay: [12582912, 16384000)
#define WB_HEAD_ELEMS 12582912

typedef __bf16 bf16x8 __attribute__((ext_vector_type(8)));
typedef float  f32x4  __attribute__((ext_vector_type(4)));
typedef unsigned int u32x4v __attribute__((ext_vector_type(4)));

// ---------------------------------------------------------------------------
// helpers
// ---------------------------------------------------------------------------
__device__ __forceinline__ float sigmoid_f(float x) {
    return 1.0f / (1.0f + __expf(-x));
}
__device__ __forceinline__ float tanh_f(float x) {
    float a = fabsf(x);
    float e = __expf(-2.0f * a);
    float r = (1.0f - e) / (1.0f + e);
    return copysignf(r, x);
}
__device__ __forceinline__ float sel4(float a0, float a1, float a2, float a3, int j) {
    float lo = (j & 1) ? a1 : a0;
    float hi = (j & 1) ? a3 : a2;
    return (j & 2) ? hi : lo;
}
__device__ __forceinline__ unsigned short f2bf_u16(float f) {
    union { float f; unsigned u; } v; v.f = f;
    unsigned r = v.u + 0x7fffu + ((v.u >> 16) & 1u);
    return (unsigned short)(r >> 16);
}

// ---------------------------------------------------------------------------
// Kernel 0: xp[s][r] = xs[s] . W_ih[r] + b_ih[r] + b_hh[r]
// ---------------------------------------------------------------------------
__global__ __launch_bounds__(256) void xproj_kernel(
    const float* __restrict__ features,
    const int*   __restrict__ captions,
    const float* __restrict__ emb,
    const float* __restrict__ W_ih,
    const float* __restrict__ b_ih,
    const float* __restrict__ b_hh,
    float* __restrict__ xp)            // [STEPS][GROWS]
{
    __shared__ float As[64][65];
    __shared__ float Bs[64][65];
    const int tid = threadIdx.x;
    const int tx = tid & 15, ty = tid >> 4;
    const int r0 = blockIdx.x * 64;
    const int s0 = blockIdx.y * 64;
    float accv[4][4] = {};

    for (int k0 = 0; k0 < EMBED; k0 += 64) {
#pragma unroll
        for (int i = 0; i < 4; ++i) {
            const int idx = tid + i * 256;
            const int row = idx >> 4, q = idx & 15;
            const int s = s0 + row, sb = s >> 6, st = s & 63;
            const float* xr = (st == 0)
                ? (features + (size_t)sb * EMBED)
                : (emb + (size_t)captions[sb * TCAP + st - 1] * EMBED);
            const float4 a = *(const float4*)(xr + k0 + q * 4);
            As[row][q * 4 + 0] = a.x; As[row][q * 4 + 1] = a.y;
            As[row][q * 4 + 2] = a.z; As[row][q * 4 + 3] = a.w;
            const float4 b = *(const float4*)(W_ih + (size_t)(r0 + row) * EMBED + k0 + q * 4);
            Bs[row][q * 4 + 0] = b.x; Bs[row][q * 4 + 1] = b.y;
            Bs[row][q * 4 + 2] = b.z; Bs[row][q * 4 + 3] = b.w;
        }
        __syncthreads();
#pragma unroll 16
        for (int kk = 0; kk < 64; ++kk) {
            float av[4], bv[4];
#pragma unroll
            for (int i = 0; i < 4; ++i) av[i] = As[ty * 4 + i][kk];
#pragma unroll
            for (int j = 0; j < 4; ++j) bv[j] = Bs[tx * 4 + j][kk];
#pragma unroll
            for (int i = 0; i < 4; ++i)
#pragma unroll
                for (int j = 0; j < 4; ++j)
                    accv[i][j] = fmaf(av[i], bv[j], accv[i][j]);
        }
        __syncthreads();
    }
#pragma unroll
    for (int j = 0; j < 4; ++j) {
        const int r = r0 + tx * 4 + j;
        const float bb = b_ih[r] + b_hh[r];
#pragma unroll
        for (int i = 0; i < 4; ++i)
            xp[(size_t)(s0 + ty * 4 + i) * GROWS + r] = accv[i][j] + bb;
    }
}

// ---------------------------------------------------------------------------
// Kernel 1: persistent sequential LSTM scan + embedded W_out converter.
// WGs 0..31: scan (128 waves own 4 h elements each, W_hh in VGPRs).
// WGs 32..255: convert W_out[0..WB_HEAD_ELEMS) fp32->bf16 on idle CUs.
// (ROUND-4 ARCHITECTURE — best measured: scan 1992us, total 2170us.
//  Fusing the logits GEMM into this kernel was tried twice (r9: +460us,
//  r10: +714us interference) and is structurally unprofitable.)
//
// Scan sync protocol (relaxed agent atomics for stores, NO fences/flags):
//   producer lane: one tagged u64 store (s+1)<<32 | h_bits. Immediately.
//   consumer: 4 waves each poll a distinct quarter (2 u64/lane) with ONE
//     fused-asm global_load_dwordx4 sc0 sc1 + vmcnt(0) (r8/r9/r10-proven;
//     load+wait MUST share one asm stmt with early-clobber output — split
//     issue/wait lets regalloc clobber in-flight dests, the r6/r7 bug),
//     verify tags == s, write floats into LDS hlds[s&1][..], ONE
//     __syncthreads (full barrier — raw s_barrier is IntrNoMem and lets
//     LDS reads hoist above it, the r6 bug), all lanes read h from LDS.
// Slot-reuse safety: any wave that published version s+1 already read
// version s; a writer of s+2 (same slot as s) consumed ALL of s+1 =>
// every wave finished reading s. Tags verify every word regardless.
// hbuf must be zeroed before launch (version 0 == zeros, tag 0).
// ---------------------------------------------------------------------------
__global__ __launch_bounds__(256, 1) void lstm_scan_kernel(
    const float* __restrict__ W_hh,
    const float* __restrict__ xp,              // [STEPS][GROWS]
    unsigned long long* __restrict__ hbuf,     // [2][HIDDEN]
    float* __restrict__ hs32,                  // [STEPS][HIDDEN]
    __bf16* __restrict__ hsbf,                 // [STEPS][HIDDEN]
    const float* __restrict__ W_out,           // converter input
    unsigned short* __restrict__ Wb,           // converter output (bf16 bits)
    const int wbf)
{
    const int tid = threadIdx.x;

    if (blockIdx.x >= 32) {
        // ---- embedded converter (runs on CUs the scan leaves idle) ----
        if (!wbf) return;
        const int cb = blockIdx.x - 32;              // 0..223
        const int stride = 224 * 256 * 4;
        for (int i = (cb * 256 + tid) * 4; i < WB_HEAD_ELEMS; i += stride) {
            const float4 v = *(const float4*)(W_out + i);
            ushort4 o;
            o.x = f2bf_u16(v.x); o.y = f2bf_u16(v.y);
            o.z = f2bf_u16(v.z); o.w = f2bf_u16(v.w);
            *(ushort4*)(Wb + i) = o;
        }
        return;
    }

    const int rg  = tid >> 6;
    const int kc  = tid & 63;
    const int w   = blockIdx.x * 4 + rg;   // global wave 0..127
    const int j0  = w * 4;

    __shared__ float hlds[2][HIDDEN];      // double-buffered h broadcast

    // lane -> (gate, elem) ownership after fold
    const int t_own  = ((kc & 1) << 1) | ((kc >> 1) & 1);
    const int jj_own = (((kc >> 2) & 1) << 1) | ((kc >> 3) & 1);
    const int row_own = t_own * HIDDEN + j0 + jj_own;

    // ---- W_hh slice into registers: 16 rows x 8 k-chunk per lane ----
    float Whh[4][4][8];
#pragma unroll
    for (int t = 0; t < 4; ++t) {
#pragma unroll
        for (int jj = 0; jj < 4; ++jj) {
            const int row = t * HIDDEN + j0 + jj;
            const float4* ph = (const float4*)(W_hh + (size_t)row * HIDDEN + kc * 8);
            const float4 h0 = ph[0], h1 = ph[1];
            Whh[t][jj][0] = h0.x; Whh[t][jj][1] = h0.y; Whh[t][jj][2] = h0.z; Whh[t][jj][3] = h0.w;
            Whh[t][jj][4] = h1.x; Whh[t][jj][5] = h1.y; Whh[t][jj][6] = h1.z; Whh[t][jj][7] = h1.w;
        }
    }

    float c_state = 0.0f;
    float xpv_next = xp[row_own];          // xp for s = 0
    const int qi = rg * 128 + kc * 2;      // my quarter words

    for (int s = 0; s < STEPS; ++s) {
        const int p = s & 1;
        const unsigned expect = (unsigned)s;
        const float xpv = xpv_next;

        // prefetch next step's xp (independent of h; hides MALL latency)
        const int sn = (s + 1 < STEPS) ? (s + 1) : (STEPS - 1);
        xpv_next = xp[(size_t)sn * GROWS + row_own];

        // ---- poll my quarter: ONE fused-asm dwordx4 + vmcnt(0) ----
        const unsigned long long fa =
            (unsigned long long)(hbuf + (size_t)p * HIDDEN + qi);
        unsigned d0, d1;
        for (;;) {
            u32x4v v;
            asm volatile("global_load_dwordx4 %0, %1, off sc0 sc1\n\t"
                         "s_waitcnt vmcnt(0)"
                         : "=&v"(v) : "v"(fa) : "memory");
            if (__all((int)((v.y == expect) & (v.w == expect)))) {
                d0 = v.x; d1 = v.z; break;
            }
        }
        hlds[p][qi]     = __uint_as_float(d0);
        hlds[p][qi + 1] = __uint_as_float(d1);
        __syncthreads();

        // ---- h from LDS ----
        float hreg[8];
        {
            const float4 a = *(const float4*)&hlds[p][kc * 8];
            const float4 b = *(const float4*)&hlds[p][kc * 8 + 4];
            hreg[0] = a.x; hreg[1] = a.y; hreg[2] = a.z; hreg[3] = a.w;
            hreg[4] = b.x; hreg[5] = b.y; hreg[6] = b.z; hreg[7] = b.w;
        }

        // ---- h contribution: 16 rows x 8 k ----
        float acc[16];
#pragma unroll
        for (int t = 0; t < 4; ++t) {
#pragma unroll
            for (int jj = 0; jj < 4; ++jj) {
                float a = Whh[t][jj][0] * hreg[0];
#pragma unroll
                for (int kk = 1; kk < 8; ++kk)
                    a = fmaf(Whh[t][jj][kk], hreg[kk], a);
                acc[t * 4 + jj] = a;
            }
        }

        // ---- fold-reduce 16 x 64 lanes -> full sum per lane ----
#pragma unroll
        for (int i = 0; i < 8; ++i) {
            const float send = (kc & 1) ? acc[i] : acc[i + 8];
            const float keep = (kc & 1) ? acc[i + 8] : acc[i];
            acc[i] = keep + __shfl_xor(send, 1, 64);
        }
#pragma unroll
        for (int i = 0; i < 4; ++i) {
            const float send = (kc & 2) ? acc[i] : acc[i + 4];
            const float keep = (kc & 2) ? acc[i + 4] : acc[i];
            acc[i] = keep + __shfl_xor(send, 2, 64);
        }
#pragma unroll
        for (int i = 0; i < 2; ++i) {
            const float send = (kc & 4) ? acc[i] : acc[i + 2];
            const float keep = (kc & 4) ? acc[i + 2] : acc[i];
            acc[i] = keep + __shfl_xor(send, 4, 64);
        }
        {
            const float send = (kc & 8) ? acc[0] : acc[1];
            const float keep = (kc & 8) ? acc[1] : acc[0];
            acc[0] = keep + __shfl_xor(send, 8, 64);
        }
        float a = acc[0];
        a += __shfl_xor(a, 16, 64);
        a += __shfl_xor(a, 32, 64);
        a += xpv;   // full gate pre-activation for (t_own, jj_own)

        // ---- gather the 4 gates of MY element ----
        const float g00 = a;
        const float g01 = __shfl_xor(a, 1, 64);
        const float g10 = __shfl_xor(a, 2, 64);
        const float g11 = __shfl_xor(g01, 2, 64);
        float gi = sel4(g00, g10, g01, g11, t_own);
        float gf = sel4(g00, g10, g01, g11, t_own ^ 1);
        float gg = sel4(g00, g10, g01, g11, t_own ^ 2);
        float go = sel4(g00, g10, g01, g11, t_own ^ 3);

        gi = sigmoid_f(gi);
        gf = sigmoid_f(gf);
        gg = tanh_f(gg);
        go = sigmoid_f(go);
        c_state = gf * c_state + gi * gg;
        const float hnew = go * tanh_f(c_state);

        // ---- publish version s+1 FIRST (critical), then trace store ----
        if ((kc & 0x33) == 0) {
            const int j = j0 + jj_own;
            const unsigned long long pack =
                ((unsigned long long)(unsigned)(s + 1) << 32) |
                (unsigned long long)__float_as_uint(hnew);
            __hip_atomic_store(hbuf + (size_t)((s + 1) & 1) * HIDDEN + j, pack,
                               __ATOMIC_RELAXED, __HIP_MEMORY_SCOPE_AGENT);
            if (wbf) hsbf[(size_t)s * HIDDEN + j] = (__bf16)hnew;
            else     hs32[(size_t)s * HIDDEN + j] = hnew;
        }
    }
}

// ---------------------------------------------------------------------------
// Kernel 1b: convert the xp-protected tail of W_out after the scan.
// ---------------------------------------------------------------------------
__global__ __launch_bounds__(256) void convert_tail_kernel(
    const float* __restrict__ W, unsigned short* __restrict__ Wb,
    int lo, int n)
{
    const int stride = gridDim.x * blockDim.x * 4;
    for (int i = lo + (blockIdx.x * blockDim.x + threadIdx.x) * 4; i < n; i += stride) {
        const float4 v = *(const float4*)(W + i);
        ushort4 o;
        o.x = f2bf_u16(v.x); o.y = f2bf_u16(v.y);
        o.z = f2bf_u16(v.z); o.w = f2bf_u16(v.w);
        *(ushort4*)(Wb + i) = o;
    }
}

// ---------------------------------------------------------------------------
// Kernel 2: logits = hs_bf16 @ Wb^T + b_out via MFMA (M=1024,N=32000,K=512).
// ---------------------------------------------------------------------------
__global__ __launch_bounds__(256) void logits_mfma_kernel(
    const __bf16* __restrict__ A,
    const __bf16* __restrict__ B,
    const float* __restrict__ b_out,
    float* __restrict__ out)
{
    __shared__ char AsR[16384];
    __shared__ char BsR[16384];
    const int tid  = threadIdx.x;
    const int lane = tid & 63;
    const int wave = tid >> 6;
    const int wm = (wave >> 1) * 64;
    const int wn = (wave & 1) * 64;
    const int n0 = blockIdx.x * 128;
    const int m0 = blockIdx.y * 128;

    f32x4 acc[4][4] = {};

    for (int k0 = 0; k0 < HIDDEN; k0 += 64) {
        if (k0) __syncthreads();
#pragma unroll
        for (int i = 0; i < 4; ++i) {
            const int o   = (tid + i * 256) << 4;
            const int row = o >> 7;
            const int cb  = o & 127;
            const int sc  = cb ^ ((row & 7) << 4);
            const bf16x8 av = *(const bf16x8*)(A + (size_t)(m0 + row) * HIDDEN + k0 + (cb >> 1));
            const bf16x8 bv = *(const bf16x8*)(B + (size_t)(n0 + row) * HIDDEN + k0 + (cb >> 1));
            *(bf16x8*)(AsR + row * 128 + sc) = av;
            *(bf16x8*)(BsR + row * 128 + sc) = bv;
        }
        __syncthreads();
#pragma unroll
        for (int ks = 0; ks < 2; ++ks) {
            const int kb = ks * 64 + ((lane >> 4) << 4);
            bf16x8 af[4], bfr[4];
#pragma unroll
            for (int mi = 0; mi < 4; ++mi) {
                const int r = wm + mi * 16 + (lane & 15);
                af[mi] = *(const bf16x8*)(AsR + r * 128 + (kb ^ ((r & 7) << 4)));
            }
#pragma unroll
            for (int ni = 0; ni < 4; ++ni) {
                const int r = wn + ni * 16 + (lane & 15);
                bfr[ni] = *(const bf16x8*)(BsR + r * 128 + (kb ^ ((r & 7) << 4)));
            }
#pragma unroll
            for (int mi = 0; mi < 4; ++mi)
#pragma unroll
                for (int ni = 0; ni < 4; ++ni)
                    acc[mi][ni] = __builtin_amdgcn_mfma_f32_16x16x32_bf16(
                        af[mi], bfr[ni], acc[mi][ni], 0, 0, 0);
        }
    }

#pragma unroll
    for (int ni = 0; ni < 4; ++ni) {
        const int col = n0 + wn + ni * 16 + (lane & 15);
        const float bo = b_out[col];
#pragma unroll
        for (int mi = 0; mi < 4; ++mi) {
            const int r0 = m0 + wm + mi * 16 + ((lane >> 4) << 2);
#pragma unroll
            for (int qq = 0; qq < 4; ++qq)
                out[(size_t)(r0 + qq) * VOCAB + col] = acc[mi][ni][qq] + bo;
        }
    }
}

// ---------------------------------------------------------------------------
// Kernel 2-fallback: fp32 vector GEMM.
// ---------------------------------------------------------------------------
__global__ __launch_bounds__(256) void logits_kernel(
    const float* __restrict__ hs,
    const float* __restrict__ W_out,
    const float* __restrict__ b_out,
    float* __restrict__ out)
{
    __shared__ float As[64][65];
    __shared__ float Bs[64][65];
    const int tid = threadIdx.x;
    const int tx = tid & 15, ty = tid >> 4;
    const int v0 = blockIdx.x * 64;
    const int s0 = blockIdx.y * 64;
    float accv[4][4] = {};

    for (int k0 = 0; k0 < HIDDEN; k0 += 64) {
#pragma unroll
        for (int i = 0; i < 4; ++i) {
            const int idx = tid + i * 256;
            const int r = idx >> 4, q = idx & 15;
            const float4 a = *(const float4*)(hs + (size_t)(s0 + r) * HIDDEN + k0 + q * 4);
            As[r][q * 4 + 0] = a.x; As[r][q * 4 + 1] = a.y;
            As[r][q * 4 + 2] = a.z; As[r][q * 4 + 3] = a.w;
            const float4 b = *(const float4*)(W_out + (size_t)(v0 + r) * HIDDEN + k0 + q * 4);
            Bs[r][q * 4 + 0] = b.x; Bs[r][q * 4 + 1] = b.y;
            Bs[r][q * 4 + 2] = b.z; Bs[r][q * 4 + 3] = b.w;
        }
        __syncthreads();
#pragma unroll 16
        for (int kk = 0; kk < 64; ++kk) {
            float av[4], bv[4];
#pragma unroll
            for (int i = 0; i < 4; ++i) av[i] = As[ty * 4 + i][kk];
#pragma unroll
            for (int j = 0; j < 4; ++j) bv[j] = Bs[tx * 4 + j][kk];
#pragma unroll
            for (int i = 0; i < 4; ++i)
#pragma unroll
                for (int j = 0; j < 4; ++j)
                    accv[i][j] = fmaf(av[i], bv[j], accv[i][j]);
        }
        __syncthreads();
    }
#pragma unroll
    for (int i = 0; i < 4; ++i) {
        const int s = s0 + ty * 4 + i;
#pragma unroll
        for (int j = 0; j < 4; ++j) {
            const int v = v0 + tx * 4 + j;
            out[(size_t)s * VOCAB + v] = accv[i][j] + b_out[v];
        }
    }
}

// ---------------------------------------------------------------------------
// Kernel 3: in-place row softmax, one WG per row of 32000.
// ---------------------------------------------------------------------------
__global__ __launch_bounds__(256) void softmax_kernel(float* __restrict__ out)
{
    const int row = blockIdx.x;
    float* p = out + (size_t)row * VOCAB;
    const int tid = threadIdx.x;
    __shared__ float redm[4];
    __shared__ float reds[4];

    float m = -3.402823466e38f;
    for (int idx = tid * 4; idx < VOCAB; idx += 1024) {
        const float4 v = *(const float4*)(p + idx);
        m = fmaxf(m, fmaxf(fmaxf(v.x, v.y), fmaxf(v.z, v.w)));
    }
#pragma unroll
    for (int d = 1; d < 64; d <<= 1) m = fmaxf(m, __shfl_xor(m, d, 64));
    if ((tid & 63) == 0) redm[tid >> 6] = m;
    __syncthreads();
    m = fmaxf(fmaxf(redm[0], redm[1]), fmaxf(redm[2], redm[3]));

    float sum = 0.f;
    for (int idx = tid * 4; idx < VOCAB; idx += 1024) {
        const float4 v = *(const float4*)(p + idx);
        sum += __expf(v.x - m) + __expf(v.y - m) + __expf(v.z - m) + __expf(v.w - m);
    }
#pragma unroll
    for (int d = 1; d < 64; d <<= 1) sum += __shfl_xor(sum, d, 64);
    if ((tid & 63) == 0) reds[tid >> 6] = sum;
    __syncthreads();
    sum = reds[0] + reds[1] + reds[2] + reds[3];
    const float inv = 1.0f / sum;

    for (int idx = tid * 4; idx < VOCAB; idx += 1024) {
        const float4 v = *(const float4*)(p + idx);
        float4 o;
        o.x = __expf(v.x - m) * inv;
        o.y = __expf(v.y - m) * inv;
        o.z = __expf(v.z - m) * inv;
        o.w = __expf(v.w - m) * inv;
        *(float4*)(p + idx) = o;
    }
}

// ---------------------------------------------------------------------------
// launch
// ---------------------------------------------------------------------------
extern "C" void kernel_launch(void* const* d_in, const int* in_sizes, int n_in,
                              void* d_out, int out_size, void* d_ws, size_t ws_size,
                              hipStream_t stream)
{
    const float* features = (const float*)d_in[0];
    const int*   captions = (const int*)d_in[1];
    const float* emb      = (const float*)d_in[2];
    const float* W_ih     = (const float*)d_in[3];
    const float* W_hh     = (const float*)d_in[4];
    const float* b_ih     = (const float*)d_in[5];
    const float* b_hh     = (const float*)d_in[6];
    const float* W_out    = (const float*)d_in[7];
    const float* b_out    = (const float*)d_in[8];
    float* out = (float*)d_out;

    char* ws = (char*)d_ws;
    unsigned long long* hbuf = (unsigned long long*)(ws + WS_HBUF);
    float*              hs32 = (float*)(ws + WS_HS32);
    __bf16*             hsbf = (__bf16*)(ws + WS_HSBF);
    __bf16*             Wb   = (__bf16*)(ws + WS_WB);
    const bool mfma_ok = ws_size >= WS_NEED;
    // xp: tail 8 MB of the Wb region (mfma path; converter skips that range
    // until after the scan), or Wb region start in fallback (Wb unused).
    float* xpb = mfma_ok ? (float*)(ws + WS_WB + WS_XPOFF) : (float*)(ws + WS_WB);

    // reset tagged h words (graph-replay determinism)
    hipMemsetAsync(d_ws, 0, 8192, stream);

    xproj_kernel<<<dim3(GROWS / 64, STEPS / 64), 256, 0, stream>>>(
        features, captions, emb, W_ih, b_ih, b_hh, xpb);

    lstm_scan_kernel<<<mfma_ok ? 256 : 32, 256, 0, stream>>>(
        W_hh, xpb, hbuf, hs32, hsbf,
        W_out, (unsigned short*)Wb, mfma_ok ? 1 : 0);

    if (mfma_ok) {
        convert_tail_kernel<<<512, 256, 0, stream>>>(
            W_out, (unsigned short*)Wb, WB_HEAD_ELEMS, VOCAB * HIDDEN);
        logits_mfma_kernel<<<dim3(VOCAB / 128, STEPS / 128), 256, 0, stream>>>(
            hsbf, Wb, b_out, out);
    } else {
        logits_kernel<<<dim3(VOCAB / 64, STEPS / 64), 256, 0, stream>>>(
            hs32, W_out, b_out, out);
    }
    softmax_kernel<<<STEPS, 256, 0, stream>>>(out);
}

// Round 12
// 1907.767 us; speedup vs baseline: 1.4662x; 1.0471x over previous
//
#include <hip/hip_runtime.h>
#include <cstdint>
#include <cstddef>

#define EMBED  256
#define HIDDEN 512
#define VOCAB  32000
#define BATCH  16
#define TCAP   63
#define STEPS  1024   // BATCH * (TCAP + 1)
#define GROWS  2048   // 4 * HIDDEN gate rows

// ws layout (bytes)  — round-4/11 proven layout
#define WS_HBUF  0          // u64 [2][512] tagged h words  (8 KB)
#define WS_HS32  8192       // float[1024][512]             (2 MB)
#define WS_HSBF  2105344    // bf16 [1024][512]             (1 MB)
#define WS_WB    3153920    // bf16 [32000][512]            (32 MB)
#define WS_XPOFF (24u * 1024u * 1024u)     // xp lives in Wb's tail 8 MB
#define WS_NEED  36708352ull
// Wb elements protected by xp overlay: [12582912, 16384000)
#define WB_HEAD_ELEMS 12582912

typedef __bf16 bf16x8 __attribute__((ext_vector_type(8)));
typedef float  f32x4  __attribute__((ext_vector_type(4)));
typedef unsigned int u32x4v __attribute__((ext_vector_type(4)));

// ---------------------------------------------------------------------------
// helpers
// ---------------------------------------------------------------------------
__device__ __forceinline__ float sigmoid_f(float x) {
    return 1.0f / (1.0f + __expf(-x));
}
__device__ __forceinline__ float tanh_f(float x) {
    float a = fabsf(x);
    float e = __expf(-2.0f * a);
    float r = (1.0f - e) / (1.0f + e);
    return copysignf(r, x);
}
__device__ __forceinline__ float sel4(float a0, float a1, float a2, float a3, int j) {
    float lo = (j & 1) ? a1 : a0;
    float hi = (j & 1) ? a3 : a2;
    return (j & 2) ? hi : lo;
}
__device__ __forceinline__ unsigned short f2bf_u16(float f) {
    union { float f; unsigned u; } v; v.f = f;
    unsigned r = v.u + 0x7fffu + ((v.u >> 16) & 1u);
    return (unsigned short)(r >> 16);
}

// ---------------------------------------------------------------------------
// Kernel 0: xp[s][r] = xs[s] . W_ih[r] + b_ih[r] + b_hh[r]
// ---------------------------------------------------------------------------
__global__ __launch_bounds__(256) void xproj_kernel(
    const float* __restrict__ features,
    const int*   __restrict__ captions,
    const float* __restrict__ emb,
    const float* __restrict__ W_ih,
    const float* __restrict__ b_ih,
    const float* __restrict__ b_hh,
    float* __restrict__ xp)            // [STEPS][GROWS]
{
    __shared__ float As[64][65];
    __shared__ float Bs[64][65];
    const int tid = threadIdx.x;
    const int tx = tid & 15, ty = tid >> 4;
    const int r0 = blockIdx.x * 64;
    const int s0 = blockIdx.y * 64;
    float accv[4][4] = {};

    for (int k0 = 0; k0 < EMBED; k0 += 64) {
#pragma unroll
        for (int i = 0; i < 4; ++i) {
            const int idx = tid + i * 256;
            const int row = idx >> 4, q = idx & 15;
            const int s = s0 + row, sb = s >> 6, st = s & 63;
            const float* xr = (st == 0)
                ? (features + (size_t)sb * EMBED)
                : (emb + (size_t)captions[sb * TCAP + st - 1] * EMBED);
            const float4 a = *(const float4*)(xr + k0 + q * 4);
            As[row][q * 4 + 0] = a.x; As[row][q * 4 + 1] = a.y;
            As[row][q * 4 + 2] = a.z; As[row][q * 4 + 3] = a.w;
            const float4 b = *(const float4*)(W_ih + (size_t)(r0 + row) * EMBED + k0 + q * 4);
            Bs[row][q * 4 + 0] = b.x; Bs[row][q * 4 + 1] = b.y;
            Bs[row][q * 4 + 2] = b.z; Bs[row][q * 4 + 3] = b.w;
        }
        __syncthreads();
#pragma unroll 16
        for (int kk = 0; kk < 64; ++kk) {
            float av[4], bv[4];
#pragma unroll
            for (int i = 0; i < 4; ++i) av[i] = As[ty * 4 + i][kk];
#pragma unroll
            for (int j = 0; j < 4; ++j) bv[j] = Bs[tx * 4 + j][kk];
#pragma unroll
            for (int i = 0; i < 4; ++i)
#pragma unroll
                for (int j = 0; j < 4; ++j)
                    accv[i][j] = fmaf(av[i], bv[j], accv[i][j]);
        }
        __syncthreads();
    }
#pragma unroll
    for (int j = 0; j < 4; ++j) {
        const int r = r0 + tx * 4 + j;
        const float bb = b_ih[r] + b_hh[r];
#pragma unroll
        for (int i = 0; i < 4; ++i)
            xp[(size_t)(s0 + ty * 4 + i) * GROWS + r] = accv[i][j] + bb;
    }
}

// ---------------------------------------------------------------------------
// Kernel 1: persistent sequential LSTM scan + embedded W_out converter.
// WGs 0..31: scan (128 waves own 4 h elements each, W_hh in VGPRs).
// WGs 32..255: convert W_out[0..WB_HEAD_ELEMS) fp32->bf16 on idle CUs.
// (ROUND-11 WINNER — scan 1767us. Unchanged this round.)
//
// Scan sync protocol (relaxed agent atomics for stores, NO fences/flags):
//   producer lane: one tagged u64 store (s+1)<<32 | h_bits. Immediately.
//   consumer: 4 waves each poll a distinct quarter (2 u64/lane) with ONE
//     fused-asm global_load_dwordx4 sc0 sc1 + vmcnt(0) (load+wait MUST
//     share one asm stmt with early-clobber output — split issue/wait lets
//     regalloc clobber in-flight dests, the r6/r7 bug), verify tags == s,
//     write floats into LDS hlds[s&1][..], ONE __syncthreads (full barrier
//     — raw s_barrier is IntrNoMem and lets LDS reads hoist above it, the
//     r6 bug), all lanes read h from LDS.
// Slot-reuse safety: any wave that published version s+1 already read
// version s; a writer of s+2 (same slot as s) consumed ALL of s+1 =>
// every wave finished reading s. Tags verify every word regardless.
// hbuf must be zeroed before launch (version 0 == zeros, tag 0).
// ---------------------------------------------------------------------------
__global__ __launch_bounds__(256, 1) void lstm_scan_kernel(
    const float* __restrict__ W_hh,
    const float* __restrict__ xp,              // [STEPS][GROWS]
    unsigned long long* __restrict__ hbuf,     // [2][HIDDEN]
    float* __restrict__ hs32,                  // [STEPS][HIDDEN]
    __bf16* __restrict__ hsbf,                 // [STEPS][HIDDEN]
    const float* __restrict__ W_out,           // converter input
    unsigned short* __restrict__ Wb,           // converter output (bf16 bits)
    const int wbf)
{
    const int tid = threadIdx.x;

    if (blockIdx.x >= 32) {
        // ---- embedded converter (runs on CUs the scan leaves idle) ----
        if (!wbf) return;
        const int cb = blockIdx.x - 32;              // 0..223
        const int stride = 224 * 256 * 4;
        for (int i = (cb * 256 + tid) * 4; i < WB_HEAD_ELEMS; i += stride) {
            const float4 v = *(const float4*)(W_out + i);
            ushort4 o;
            o.x = f2bf_u16(v.x); o.y = f2bf_u16(v.y);
            o.z = f2bf_u16(v.z); o.w = f2bf_u16(v.w);
            *(ushort4*)(Wb + i) = o;
        }
        return;
    }

    const int rg  = tid >> 6;
    const int kc  = tid & 63;
    const int w   = blockIdx.x * 4 + rg;   // global wave 0..127
    const int j0  = w * 4;

    __shared__ float hlds[2][HIDDEN];      // double-buffered h broadcast

    // lane -> (gate, elem) ownership after fold
    const int t_own  = ((kc & 1) << 1) | ((kc >> 1) & 1);
    const int jj_own = (((kc >> 2) & 1) << 1) | ((kc >> 3) & 1);
    const int row_own = t_own * HIDDEN + j0 + jj_own;

    // ---- W_hh slice into registers: 16 rows x 8 k-chunk per lane ----
    float Whh[4][4][8];
#pragma unroll
    for (int t = 0; t < 4; ++t) {
#pragma unroll
        for (int jj = 0; jj < 4; ++jj) {
            const int row = t * HIDDEN + j0 + jj;
            const float4* ph = (const float4*)(W_hh + (size_t)row * HIDDEN + kc * 8);
            const float4 h0 = ph[0], h1 = ph[1];
            Whh[t][jj][0] = h0.x; Whh[t][jj][1] = h0.y; Whh[t][jj][2] = h0.z; Whh[t][jj][3] = h0.w;
            Whh[t][jj][4] = h1.x; Whh[t][jj][5] = h1.y; Whh[t][jj][6] = h1.z; Whh[t][jj][7] = h1.w;
        }
    }

    float c_state = 0.0f;
    float xpv_next = xp[row_own];          // xp for s = 0
    const int qi = rg * 128 + kc * 2;      // my quarter words

    for (int s = 0; s < STEPS; ++s) {
        const int p = s & 1;
        const unsigned expect = (unsigned)s;
        const float xpv = xpv_next;

        // prefetch next step's xp (independent of h; hides MALL latency)
        const int sn = (s + 1 < STEPS) ? (s + 1) : (STEPS - 1);
        xpv_next = xp[(size_t)sn * GROWS + row_own];

        // ---- poll my quarter: ONE fused-asm dwordx4 + vmcnt(0) ----
        const unsigned long long fa =
            (unsigned long long)(hbuf + (size_t)p * HIDDEN + qi);
        unsigned d0, d1;
        for (;;) {
            u32x4v v;
            asm volatile("global_load_dwordx4 %0, %1, off sc0 sc1\n\t"
                         "s_waitcnt vmcnt(0)"
                         : "=&v"(v) : "v"(fa) : "memory");
            if (__all((int)((v.y == expect) & (v.w == expect)))) {
                d0 = v.x; d1 = v.z; break;
            }
        }
        hlds[p][qi]     = __uint_as_float(d0);
        hlds[p][qi + 1] = __uint_as_float(d1);
        __syncthreads();

        // ---- h from LDS ----
        float hreg[8];
        {
            const float4 a = *(const float4*)&hlds[p][kc * 8];
            const float4 b = *(const float4*)&hlds[p][kc * 8 + 4];
            hreg[0] = a.x; hreg[1] = a.y; hreg[2] = a.z; hreg[3] = a.w;
            hreg[4] = b.x; hreg[5] = b.y; hreg[6] = b.z; hreg[7] = b.w;
        }

        // ---- h contribution: 16 rows x 8 k ----
        float acc[16];
#pragma unroll
        for (int t = 0; t < 4; ++t) {
#pragma unroll
            for (int jj = 0; jj < 4; ++jj) {
                float a = Whh[t][jj][0] * hreg[0];
#pragma unroll
                for (int kk = 1; kk < 8; ++kk)
                    a = fmaf(Whh[t][jj][kk], hreg[kk], a);
                acc[t * 4 + jj] = a;
            }
        }

        // ---- fold-reduce 16 x 64 lanes -> full sum per lane ----
#pragma unroll
        for (int i = 0; i < 8; ++i) {
            const float send = (kc & 1) ? acc[i] : acc[i + 8];
            const float keep = (kc & 1) ? acc[i + 8] : acc[i];
            acc[i] = keep + __shfl_xor(send, 1, 64);
        }
#pragma unroll
        for (int i = 0; i < 4; ++i) {
            const float send = (kc & 2) ? acc[i] : acc[i + 4];
            const float keep = (kc & 2) ? acc[i + 4] : acc[i];
            acc[i] = keep + __shfl_xor(send, 2, 64);
        }
#pragma unroll
        for (int i = 0; i < 2; ++i) {
            const float send = (kc & 4) ? acc[i] : acc[i + 2];
            const float keep = (kc & 4) ? acc[i + 2] : acc[i];
            acc[i] = keep + __shfl_xor(send, 4, 64);
        }
        {
            const float send = (kc & 8) ? acc[0] : acc[1];
            const float keep = (kc & 8) ? acc[1] : acc[0];
            acc[0] = keep + __shfl_xor(send, 8, 64);
        }
        float a = acc[0];
        a += __shfl_xor(a, 16, 64);
        a += __shfl_xor(a, 32, 64);
        a += xpv;   // full gate pre-activation for (t_own, jj_own)

        // ---- gather the 4 gates of MY element ----
        const float g00 = a;
        const float g01 = __shfl_xor(a, 1, 64);
        const float g10 = __shfl_xor(a, 2, 64);
        const float g11 = __shfl_xor(g01, 2, 64);
        float gi = sel4(g00, g10, g01, g11, t_own);
        float gf = sel4(g00, g10, g01, g11, t_own ^ 1);
        float gg = sel4(g00, g10, g01, g11, t_own ^ 2);
        float go = sel4(g00, g10, g01, g11, t_own ^ 3);

        gi = sigmoid_f(gi);
        gf = sigmoid_f(gf);
        gg = tanh_f(gg);
        go = sigmoid_f(go);
        c_state = gf * c_state + gi * gg;
        const float hnew = go * tanh_f(c_state);

        // ---- publish version s+1 FIRST (critical), then trace store ----
        if ((kc & 0x33) == 0) {
            const int j = j0 + jj_own;
            const unsigned long long pack =
                ((unsigned long long)(unsigned)(s + 1) << 32) |
                (unsigned long long)__float_as_uint(hnew);
            __hip_atomic_store(hbuf + (size_t)((s + 1) & 1) * HIDDEN + j, pack,
                               __ATOMIC_RELAXED, __HIP_MEMORY_SCOPE_AGENT);
            if (wbf) hsbf[(size_t)s * HIDDEN + j] = (__bf16)hnew;
            else     hs32[(size_t)s * HIDDEN + j] = hnew;
        }
    }
}

// ---------------------------------------------------------------------------
// Kernel 1b: convert the xp-protected tail of W_out after the scan.
// ---------------------------------------------------------------------------
__global__ __launch_bounds__(256) void convert_tail_kernel(
    const float* __restrict__ W, unsigned short* __restrict__ Wb,
    int lo, int n)
{
    const int stride = gridDim.x * blockDim.x * 4;
    for (int i = lo + (blockIdx.x * blockDim.x + threadIdx.x) * 4; i < n; i += stride) {
        const float4 v = *(const float4*)(W + i);
        ushort4 o;
        o.x = f2bf_u16(v.x); o.y = f2bf_u16(v.y);
        o.z = f2bf_u16(v.z); o.w = f2bf_u16(v.w);
        *(ushort4*)(Wb + i) = o;
    }
}

// ---------------------------------------------------------------------------
// Kernel 2: logits = hs_bf16 @ Wb^T + b_out via MFMA (M=1024,N=32000,K=512).
// ---------------------------------------------------------------------------
__global__ __launch_bounds__(256) void logits_mfma_kernel(
    const __bf16* __restrict__ A,
    const __bf16* __restrict__ B,
    const float* __restrict__ b_out,
    float* __restrict__ out)
{
    __shared__ char AsR[16384];
    __shared__ char BsR[16384];
    const int tid  = threadIdx.x;
    const int lane = tid & 63;
    const int wave = tid >> 6;
    const int wm = (wave >> 1) * 64;
    const int wn = (wave & 1) * 64;
    const int n0 = blockIdx.x * 128;
    const int m0 = blockIdx.y * 128;

    f32x4 acc[4][4] = {};

    for (int k0 = 0; k0 < HIDDEN; k0 += 64) {
        if (k0) __syncthreads();
#pragma unroll
        for (int i = 0; i < 4; ++i) {
            const int o   = (tid + i * 256) << 4;
            const int row = o >> 7;
            const int cb  = o & 127;
            const int sc  = cb ^ ((row & 7) << 4);
            const bf16x8 av = *(const bf16x8*)(A + (size_t)(m0 + row) * HIDDEN + k0 + (cb >> 1));
            const bf16x8 bv = *(const bf16x8*)(B + (size_t)(n0 + row) * HIDDEN + k0 + (cb >> 1));
            *(bf16x8*)(AsR + row * 128 + sc) = av;
            *(bf16x8*)(BsR + row * 128 + sc) = bv;
        }
        __syncthreads();
#pragma unroll
        for (int ks = 0; ks < 2; ++ks) {
            const int kb = ks * 64 + ((lane >> 4) << 4);
            bf16x8 af[4], bfr[4];
#pragma unroll
            for (int mi = 0; mi < 4; ++mi) {
                const int r = wm + mi * 16 + (lane & 15);
                af[mi] = *(const bf16x8*)(AsR + r * 128 + (kb ^ ((r & 7) << 4)));
            }
#pragma unroll
            for (int ni = 0; ni < 4; ++ni) {
                const int r = wn + ni * 16 + (lane & 15);
                bfr[ni] = *(const bf16x8*)(BsR + r * 128 + (kb ^ ((r & 7) << 4)));
            }
#pragma unroll
            for (int mi = 0; mi < 4; ++mi)
#pragma unroll
                for (int ni = 0; ni < 4; ++ni)
                    acc[mi][ni] = __builtin_amdgcn_mfma_f32_16x16x32_bf16(
                        af[mi], bfr[ni], acc[mi][ni], 0, 0, 0);
        }
    }

#pragma unroll
    for (int ni = 0; ni < 4; ++ni) {
        const int col = n0 + wn + ni * 16 + (lane & 15);
        const float bo = b_out[col];
#pragma unroll
        for (int mi = 0; mi < 4; ++mi) {
            const int r0 = m0 + wm + mi * 16 + ((lane >> 4) << 2);
#pragma unroll
            for (int qq = 0; qq < 4; ++qq)
                out[(size_t)(r0 + qq) * VOCAB + col] = acc[mi][ni][qq] + bo;
        }
    }
}

// ---------------------------------------------------------------------------
// Kernel 2-fallback: fp32 vector GEMM.
// ---------------------------------------------------------------------------
__global__ __launch_bounds__(256) void logits_kernel(
    const float* __restrict__ hs,
    const float* __restrict__ W_out,
    const float* __restrict__ b_out,
    float* __restrict__ out)
{
    __shared__ float As[64][65];
    __shared__ float Bs[64][65];
    const int tid = threadIdx.x;
    const int tx = tid & 15, ty = tid >> 4;
    const int v0 = blockIdx.x * 64;
    const int s0 = blockIdx.y * 64;
    float accv[4][4] = {};

    for (int k0 = 0; k0 < HIDDEN; k0 += 64) {
#pragma unroll
        for (int i = 0; i < 4; ++i) {
            const int idx = tid + i * 256;
            const int r = idx >> 4, q = idx & 15;
            const float4 a = *(const float4*)(hs + (size_t)(s0 + r) * HIDDEN + k0 + q * 4);
            As[r][q * 4 + 0] = a.x; As[r][q * 4 + 1] = a.y;
            As[r][q * 4 + 2] = a.z; As[r][q * 4 + 3] = a.w;
            const float4 b = *(const float4*)(W_out + (size_t)(v0 + r) * HIDDEN + k0 + q * 4);
            Bs[r][q * 4 + 0] = b.x; Bs[r][q * 4 + 1] = b.y;
            Bs[r][q * 4 + 2] = b.z; Bs[r][q * 4 + 3] = b.w;
        }
        __syncthreads();
#pragma unroll 16
        for (int kk = 0; kk < 64; ++kk) {
            float av[4], bv[4];
#pragma unroll
            for (int i = 0; i < 4; ++i) av[i] = As[ty * 4 + i][kk];
#pragma unroll
            for (int j = 0; j < 4; ++j) bv[j] = Bs[tx * 4 + j][kk];
#pragma unroll
            for (int i = 0; i < 4; ++i)
#pragma unroll
                for (int j = 0; j < 4; ++j)
                    accv[i][j] = fmaf(av[i], bv[j], accv[i][j]);
        }
        __syncthreads();
    }
#pragma unroll
    for (int i = 0; i < 4; ++i) {
        const int s = s0 + ty * 4 + i;
#pragma unroll
        for (int j = 0; j < 4; ++j) {
            const int v = v0 + tx * 4 + j;
            out[(size_t)s * VOCAB + v] = accv[i][j] + b_out[v];
        }
    }
}

// ---------------------------------------------------------------------------
// Kernel 3: single-read register-resident online softmax.
// One 1024-thread WG per row; each thread holds 32 row elements in
// registers (static indexing). Online (m,l) per thread -> wave shuffle
// reduce -> 16-wave LDS reduce -> normalize from registers.
// HBM traffic: 1 read + 1 write pass (was 3 reads + 1 write).
// VOCAB = 32000 = 7*4096 + 3328: chunk 7 is guarded (tid*4 < 3328).
// ---------------------------------------------------------------------------
__global__ __launch_bounds__(1024, 1) void softmax_kernel(float* __restrict__ out)
{
    __shared__ float redm[16];
    __shared__ float redl[16];
    const int row = blockIdx.x;
    float* p = out + (size_t)row * VOCAB;
    const int tid  = threadIdx.x;        // 0..1023
    const int lane = tid & 63, wv = tid >> 6;

    float r[32];
    float m = -3.402823466e38f, l = 0.0f;
#pragma unroll
    for (int c = 0; c < 8; ++c) {
        const int i = c * 4096 + tid * 4;
        if (i < VOCAB) {
            const float4 v = *(const float4*)(p + i);
            r[c * 4 + 0] = v.x; r[c * 4 + 1] = v.y;
            r[c * 4 + 2] = v.z; r[c * 4 + 3] = v.w;
            const float m4 = fmaxf(fmaxf(v.x, v.y), fmaxf(v.z, v.w));
            const float mn = fmaxf(m, m4);
            l = l * __expf(m - mn)
              + __expf(v.x - mn) + __expf(v.y - mn)
              + __expf(v.z - mn) + __expf(v.w - mn);
            m = mn;
        }
    }

    // wave-level (m,l) merge
#pragma unroll
    for (int d = 1; d < 64; d <<= 1) {
        const float mo = __shfl_xor(m, d, 64);
        const float lo = __shfl_xor(l, d, 64);
        const float mn = fmaxf(m, mo);
        l = l * __expf(m - mn) + lo * __expf(mo - mn);
        m = mn;
    }
    if (lane == 0) { redm[wv] = m; redl[wv] = l; }
    __syncthreads();

    // combine 16 wave partials (uniform across threads)
    m = redm[0]; l = redl[0];
#pragma unroll
    for (int i2 = 1; i2 < 16; ++i2) {
        const float mo = redm[i2], lo = redl[i2];
        const float mn = fmaxf(m, mo);
        l = l * __expf(m - mn) + lo * __expf(mo - mn);
        m = mn;
    }
    const float inv = 1.0f / l;

#pragma unroll
    for (int c = 0; c < 8; ++c) {
        const int i = c * 4096 + tid * 4;
        if (i < VOCAB) {
            float4 o;
            o.x = __expf(r[c * 4 + 0] - m) * inv;
            o.y = __expf(r[c * 4 + 1] - m) * inv;
            o.z = __expf(r[c * 4 + 2] - m) * inv;
            o.w = __expf(r[c * 4 + 3] - m) * inv;
            *(float4*)(p + i) = o;
        }
    }
}

// ---------------------------------------------------------------------------
// launch
// ---------------------------------------------------------------------------
extern "C" void kernel_launch(void* const* d_in, const int* in_sizes, int n_in,
                              void* d_out, int out_size, void* d_ws, size_t ws_size,
                              hipStream_t stream)
{
    const float* features = (const float*)d_in[0];
    const int*   captions = (const int*)d_in[1];
    const float* emb      = (const float*)d_in[2];
    const float* W_ih     = (const float*)d_in[3];
    const float* W_hh     = (const float*)d_in[4];
    const float* b_ih     = (const float*)d_in[5];
    const float* b_hh     = (const float*)d_in[6];
    const float* W_out    = (const float*)d_in[7];
    const float* b_out    = (const float*)d_in[8];
    float* out = (float*)d_out;

    char* ws = (char*)d_ws;
    unsigned long long* hbuf = (unsigned long long*)(ws + WS_HBUF);
    float*              hs32 = (float*)(ws + WS_HS32);
    __bf16*             hsbf = (__bf16*)(ws + WS_HSBF);
    __bf16*             Wb   = (__bf16*)(ws + WS_WB);
    const bool mfma_ok = ws_size >= WS_NEED;
    // xp: tail 8 MB of the Wb region (mfma path; converter skips that range
    // until after the scan), or Wb region start in fallback (Wb unused).
    float* xpb = mfma_ok ? (float*)(ws + WS_WB + WS_XPOFF) : (float*)(ws + WS_WB);

    // reset tagged h words (graph-replay determinism)
    hipMemsetAsync(d_ws, 0, 8192, stream);

    xproj_kernel<<<dim3(GROWS / 64, STEPS / 64), 256, 0, stream>>>(
        features, captions, emb, W_ih, b_ih, b_hh, xpb);

    lstm_scan_kernel<<<mfma_ok ? 256 : 32, 256, 0, stream>>>(
        W_hh, xpb, hbuf, hs32, hsbf,
        W_out, (unsigned short*)Wb, mfma_ok ? 1 : 0);

    if (mfma_ok) {
        convert_tail_kernel<<<512, 256, 0, stream>>>(
            W_out, (unsigned short*)Wb, WB_HEAD_ELEMS, VOCAB * HIDDEN);
        logits_mfma_kernel<<<dim3(VOCAB / 128, STEPS / 128), 256, 0, stream>>>(
            hsbf, Wb, b_out, out);
    } else {
        logits_kernel<<<dim3(VOCAB / 64, STEPS / 64), 256, 0, stream>>>(
            hs32, W_out, b_out, out);
    }
    softmax_kernel<<<STEPS, 1024, 0, stream>>>(out);
}